// Round 11
// baseline (355.392 us; speedup 1.0000x reference)
//
#include <hip/hip_runtime.h>
#include <hip/hip_bf16.h>
#include <cstdint>
#include <cstddef>

#define DIM    1024
#define NHEAD  16
#define HDIM   64
#define HIDDEN 4096
#define TSEQ   2048
#define TOKENS 4096  // B*T

typedef __attribute__((ext_vector_type(4))) float  f32x4;
typedef __attribute__((ext_vector_type(8))) short  short8;
typedef __attribute__((ext_vector_type(8))) __bf16 bf16x8;

__device__ __forceinline__ short f2bf(float f) {
    union { float f; uint32_t u; } v; v.f = f;
    uint32_t u = v.u;
    uint32_t r = (u + 0x7fffu + ((u >> 16) & 1u)) >> 16;  // RNE
    return (short)r;
}

__device__ __forceinline__ float bf2f(short s) {
    uint32_t u = ((uint32_t)(uint16_t)s) << 16;
    return __builtin_bit_cast(float, u);
}

__device__ __forceinline__ f32x4 mfma_bf16(short8 a, short8 b, f32x4 c) {
    return __builtin_amdgcn_mfma_f32_16x16x32_bf16(
        __builtin_bit_cast(bf16x8, a), __builtin_bit_cast(bf16x8, b), c, 0, 0, 0);
}

// lgkm-only barrier: does NOT drain vmem, keeps register prefetches
// in flight across barriers.
__device__ __forceinline__ void barrier_lds() {
    asm volatile("s_waitcnt lgkmcnt(0)\n\ts_barrier" ::: "memory");
}

// ---------------------------------------------------------------------------
// Weight transpose + fp32->bf16 convert:  W[K][N] -> Wt[N][K] (bf16)
// ---------------------------------------------------------------------------
__global__ __launch_bounds__(256) void transpose_w(
    const float* __restrict__ W, short* __restrict__ Wt, int K, int N)
{
    __shared__ float tile[64][65];
    const int tid = threadIdx.x;
    const int n0 = blockIdx.x * 64, k0 = blockIdx.y * 64;
    for (int i = tid; i < 4096; i += 256) {
        int r = i >> 6, c = i & 63;
        tile[r][c] = W[(size_t)(k0 + r) * N + n0 + c];
    }
    __syncthreads();
    for (int i = tid; i < 4096; i += 256) {
        int r = i >> 6, c = i & 63;
        Wt[(size_t)(n0 + r) * K + k0 + c] = f2bf(tile[c][r]);
    }
}

// ---------------------------------------------------------------------------
// V transpose: qkv [4096][3072] (V at col 2048 + h*64) -> Vt[bh][64][2048]
// ---------------------------------------------------------------------------
__global__ __launch_bounds__(256) void transpose_v(
    const short* __restrict__ qkv, short* __restrict__ Vt)
{
    __shared__ short tile[64][72];
    const int tid = threadIdx.x;
    const int s0 = blockIdx.x * 64, bh = blockIdx.y;
    const int b = bh >> 4, h = bh & 15;
    const short* src = qkv + ((size_t)(b * TSEQ + s0)) * 3072 + 2048 + h * 64;
    for (int i = tid; i < 512; i += 256) {
        int r = i >> 3, cg = i & 7;
        *(short8*)&tile[r][cg * 8] = *(const short8*)(src + (size_t)r * 3072 + cg * 8);
    }
    __syncthreads();
    short* dst = Vt + ((size_t)bh * 64) * TSEQ + s0;
    for (int i = tid; i < 512; i += 256) {
        int d = i >> 3, sg = i & 7;
        short8 o;
#pragma unroll
        for (int j = 0; j < 8; ++j) o[j] = tile[sg * 8 + j][d];
        *(short8*)(dst + (size_t)d * TSEQ + sg * 8) = o;
    }
}

// ---------------------------------------------------------------------------
// RMSNorm: fp32 in -> bf16 out. One block per token.
// ---------------------------------------------------------------------------
__global__ __launch_bounds__(256) void rmsnorm_k(
    const float* __restrict__ x, const float* __restrict__ g, short* __restrict__ out)
{
    const int t = blockIdx.x, tid = threadIdx.x;
    const int wave = tid >> 6, lane = tid & 63;
    const float4 v = ((const float4*)(x + (size_t)t * DIM))[tid];
    float ss = v.x * v.x + v.y * v.y + v.z * v.z + v.w * v.w;
#pragma unroll
    for (int d = 1; d < 64; d <<= 1) ss += __shfl_xor(ss, d, 64);
    __shared__ float red[4];
    if (lane == 0) red[wave] = ss;
    __syncthreads();
    float tot = red[0] + red[1] + red[2] + red[3];
    float rn = rsqrtf(tot * (1.0f / (float)DIM) + 1e-6f);
    const float4 gv = ((const float4*)g)[tid];
    short4 ov = make_short4(f2bf(v.x * rn * gv.x), f2bf(v.y * rn * gv.y),
                            f2bf(v.z * rn * gv.z), f2bf(v.w * rn * gv.w));
    ((short4*)(out + (size_t)t * DIM))[tid] = ov;
}

// ---------------------------------------------------------------------------
// bf16 GEMM: C[M][N] = A[M][K] * Bt[N][K]^T, 128x128 tile, BK=64, 4 waves.
// R5 skeleton (proven best): register staging, BK=64, chunk-XOR swizzle
// (chunk ^= row&7) on BOTH ds_write and ds_read -> reads 2-way (free).
// Grid m-fastest: each XCD pins an m-subset, A rows stay L2-resident.
// EPI: 0 = bf16 out, 1 = fp32 out + fp32 residual, 2 = SiLU -> bf16 out,
//      3 = BF16 partial out at Cout + z*M*N (split-K)
// ---------------------------------------------------------------------------
template <int EPI>
__global__ __launch_bounds__(256) void gemm_bt(
    const short* __restrict__ A, const short* __restrict__ Bt,
    void* __restrict__ Cout, const float* __restrict__ res,
    int M, int N, int K)
{
    __shared__ short As[128 * 64];
    __shared__ short Bs[128 * 64];
    const int tid  = threadIdx.x;
    const int wave = tid >> 6, lane = tid & 63;
    const int lm = lane & 15, quad = lane >> 4;
    const int wm = wave & 1, wn = wave >> 1;
    const int m0 = blockIdx.x * 128, n0 = blockIdx.y * 128;  // m fastest
    const int Ksl = K / gridDim.z;
    const int kbeg = blockIdx.z * Ksl;
    const int nIter = Ksl >> 6;  // >= 4 in all launches here

    const f32x4 zero = {0.f, 0.f, 0.f, 0.f};
    f32x4 acc[4][4];
#pragma unroll
    for (int i = 0; i < 4; ++i)
#pragma unroll
        for (int j = 0; j < 4; ++j) acc[i][j] = zero;

    // staging map: thread t covers rows (t>>3)+j*32, 16B chunk (t&7), j=0..3
    const int srow = tid >> 3;            // 0..31
    const int scol = (tid & 7) * 8;       // shorts
    const int pcol = ((tid & 7) ^ (srow & 7)) * 8;  // XOR-swizzled chunk
    const short* Ap = A + (size_t)(m0 + srow) * K + kbeg + scol;
    const short* Bp = Bt + (size_t)(n0 + srow) * K + kbeg + scol;

    short8 ar[4], br[4];  // one 64-K tile in registers (prefetch)

    auto loadtile = [&]() {
#pragma unroll
        for (int j = 0; j < 4; ++j) {
            ar[j] = *(const short8*)(Ap + (size_t)(j * 32) * K);
            br[j] = *(const short8*)(Bp + (size_t)(j * 32) * K);
        }
        Ap += 64; Bp += 64;
    };

    auto storetile = [&]() {
#pragma unroll
        for (int j = 0; j < 4; ++j) {
            *(short8*)&As[(srow + j * 32) * 64 + pcol] = ar[j];
            *(short8*)&Bs[(srow + j * 32) * 64 + pcol] = br[j];
        }
    };

    const int e = lm & 7;
    auto compute = [&]() {
#pragma unroll
        for (int kk = 0; kk < 2; ++kk) {
            short8 af[4], bf[4];
#pragma unroll
            for (int mt = 0; mt < 4; ++mt)
                af[mt] = *(const short8*)&As[(wm * 64 + mt * 16 + lm) * 64 +
                                             ((((kk << 2) | quad) ^ e) << 3)];
#pragma unroll
            for (int nt = 0; nt < 4; ++nt)
                bf[nt] = *(const short8*)&Bs[(wn * 64 + nt * 16 + lm) * 64 +
                                             ((((kk << 2) | quad) ^ e) << 3)];
#pragma unroll
            for (int mt = 0; mt < 4; ++mt)
#pragma unroll
                for (int nt = 0; nt < 4; ++nt)
                    acc[mt][nt] = mfma_bf16(af[mt], bf[nt], acc[mt][nt]);
        }
    };

    loadtile();  // tile 0 -> regs

    for (int it = 0; it < nIter; ++it) {
        barrier_lds();   // all waves done reading LDS (prev compute)
        storetile();     // regs -> LDS (compiler waits vmcnt on ar/br here)
        barrier_lds();   // tile visible to all waves
        if (it + 1 < nIter) loadtile();  // prefetch next tile (covered by 32 MFMAs)
        compute();
    }

#pragma unroll
    for (int mt = 0; mt < 4; ++mt) {
#pragma unroll
        for (int r = 0; r < 4; ++r) {
            const int row = m0 + wm * 64 + mt * 16 + quad * 4 + r;
#pragma unroll
            for (int nt = 0; nt < 4; ++nt) {
                const int col = n0 + wn * 64 + nt * 16 + lm;
                const size_t idx = (size_t)row * N + col;
                const float v = acc[mt][nt][r];
                if constexpr (EPI == 0) {
                    ((short*)Cout)[idx] = f2bf(v);
                } else if constexpr (EPI == 1) {
                    ((float*)Cout)[idx] = res[idx] + v;
                } else if constexpr (EPI == 2) {
                    ((short*)Cout)[idx] = f2bf(v / (1.0f + __expf(-v)));
                } else {
                    ((short*)Cout)[(size_t)blockIdx.z * M * N + idx] = f2bf(v);
                }
            }
        }
    }
}

// ---------------------------------------------------------------------------
// Split-K combine (4 bf16 partials): out = res + sum_{s<4} p[s]
// ---------------------------------------------------------------------------
__global__ __launch_bounds__(256) void combine_k4(
    const short* __restrict__ p, const float* __restrict__ res,
    float* __restrict__ out, int n)
{
    const int i = blockIdx.x * 256 + threadIdx.x;
    if (i * 4 < n) {
        float4 v = ((const float4*)res)[i];
#pragma unroll
        for (int s = 0; s < 4; ++s) {
            short4 ps = ((const short4*)(p + (size_t)s * n))[i];
            v.x += bf2f(ps.x); v.y += bf2f(ps.y);
            v.z += bf2f(ps.z); v.w += bf2f(ps.w);
        }
        ((float4*)out)[i] = v;
    }
}

// ---------------------------------------------------------------------------
// Fused split-K combine (4 bf16 partials) + RMSNorm: one block per token.
//   x2 = res + sum p[s];  nout = bf16(x2 * rsqrt(mean(x2^2)+eps) * g)
// ---------------------------------------------------------------------------
__global__ __launch_bounds__(256) void combine_rms4(
    const short* __restrict__ p, const float* __restrict__ res,
    const float* __restrict__ g, float* __restrict__ x2out,
    short* __restrict__ nout)
{
    const int t = blockIdx.x, tid = threadIdx.x;
    const int wave = tid >> 6, lane = tid & 63;
    const size_t i4 = (size_t)t * 256 + tid;  // float4 index
    float4 v = ((const float4*)res)[i4];
#pragma unroll
    for (int s = 0; s < 4; ++s) {
        short4 ps = ((const short4*)(p + (size_t)s * TOKENS * DIM))[i4];
        v.x += bf2f(ps.x); v.y += bf2f(ps.y);
        v.z += bf2f(ps.z); v.w += bf2f(ps.w);
    }
    ((float4*)x2out)[i4] = v;
    float ss = v.x * v.x + v.y * v.y + v.z * v.z + v.w * v.w;
#pragma unroll
    for (int d = 1; d < 64; d <<= 1) ss += __shfl_xor(ss, d, 64);
    __shared__ float red[4];
    if (lane == 0) red[wave] = ss;
    __syncthreads();
    float tot = red[0] + red[1] + red[2] + red[3];
    float rn = rsqrtf(tot * (1.0f / (float)DIM) + 1e-6f);
    const float4 gv = ((const float4*)g)[tid];
    short4 ov = make_short4(f2bf(v.x * rn * gv.x), f2bf(v.y * rn * gv.y),
                            f2bf(v.z * rn * gv.z), f2bf(v.w * rn * gv.w));
    ((short4*)nout)[i4] = ov;
}

// ---------------------------------------------------------------------------
// Flash attention, causal, fixed-max softmax.
// R10: R5 pair-split skeleton. Counters (R9): swizzle killed conflicts
// (2.7M->262K) but per-element P-write XOR added VALU (31->42%) -> slower.
// Regime lesson applied: conflicts off critical path, VALU is. This round:
// (1) K/V keep the FREE swizzle (loop-invariant addressing, unpadded [64]);
// (2) P back to padded LP=72 with R5's cheap scalar-write addressing;
// (3) lsum via ones-MFMA: l[q]=sum_s P[q][s] computed by mfma(P,ones) into
//     lacc (4 MFMA/iter replaces 32 v_adds + end shuffle-reduce; also makes
//     l numerically consistent with PV's bf16 P);
// (4) band-hoisted softmax: full tiles skip the causal compare/select.
// LDS 50KB (16+16+18) -> 3 blocks/CU (was 2).
// ---------------------------------------------------------------------------
#define PLP 72
__global__ __launch_bounds__(256, 2) void attn_k(
    const short* __restrict__ qkv, const short* __restrict__ Vt,
    short* __restrict__ out)
{
    __shared__ short Ks[2][64 * 64];    // 16 KB (swizzled)
    __shared__ short Vts[2][64 * 64];   // 16 KB (swizzled)
    __shared__ short Ps[4][32 * PLP];   // 18 KB (padded, plain addressing)

    const int tid = threadIdx.x, wave = tid >> 6, lane = tid & 63;
    const int pair = wave >> 1, wv = wave & 1;
    const int lm = lane & 15, quad = lane >> 4;
    const int e = lm & 7;
    const int bh = blockIdx.x;
    const int qt = (gridDim.y - 1) - blockIdx.y;  // heavy blocks first
    const int b = bh >> 4, h = bh & 15;
    const int q0 = qt * 64;

    const int n  = qt + 1;           // total s-tiles
    const int nA = (n + 1) >> 1;     // tiles for pair A
    const int nP = pair ? (n >> 1) : nA;
    const int sbase = pair ? nA : 0;

    const int tp = tid & 127;        // thread index within pair
    const int rr = tp >> 3, cg = tp & 7;
    const int pcol = (cg ^ (rr & 7)) * 8;   // XOR-swizzled chunk (K/V staging)

    // Q fragments (loop-invariant, direct to registers)
    const short* qb = qkv + ((size_t)(b * TSEQ + q0)) * 3072 + h * 64;
    short8 aq[2][2];
#pragma unroll
    for (int mt = 0; mt < 2; ++mt)
#pragma unroll
        for (int kk = 0; kk < 2; ++kk)
            aq[mt][kk] = *(const short8*)(qb + (size_t)(wv * 32 + mt * 16 + lm) * 3072 + kk * 32 + quad * 8);

    const short* kb  = qkv + (size_t)b * TSEQ * 3072 + 1024 + h * 64;
    const short* vtb = Vt + (size_t)bh * 64 * TSEQ;

    const short ONEBF = (short)0x3F80;  // bf16 1.0
    const short8 ones8 = {ONEBF, ONEBF, ONEBF, ONEBF, ONEBF, ONEBF, ONEBF, ONEBF};

    const f32x4 zero = {0.f, 0.f, 0.f, 0.f};
    f32x4 o_acc[2][4];
    f32x4 lacc[2];  // l[q] per mt (every lane&15 holds the same row-sum)
#pragma unroll
    for (int mt = 0; mt < 2; ++mt) {
#pragma unroll
        for (int t = 0; t < 4; ++t) o_acc[mt][t] = zero;
        lacc[mt] = zero;
    }

    // initial register prefetch of this pair's first tile
    short8 kr[4], vr[4];
    if (nP > 0) {
        const size_t s0i = (size_t)sbase * 64;
#pragma unroll
        for (int j = 0; j < 4; ++j) {
            kr[j] = *(const short8*)(kb + (s0i + rr + j * 16) * 3072 + cg * 8);
            vr[j] = *(const short8*)(vtb + (size_t)(rr + j * 16) * TSEQ + s0i + cg * 8);
        }
    }

    for (int it = 0; it < nA; ++it) {
        const int st = sbase + it;
        const bool act = it < nP;
        __syncthreads();
        if (act) {
#pragma unroll
            for (int j = 0; j < 4; ++j) {
                *(short8*)&Ks[pair][(rr + j * 16) * 64 + pcol] = kr[j];
                *(short8*)&Vts[pair][(rr + j * 16) * 64 + pcol] = vr[j];
            }
        }
        __syncthreads();
        if (act && it + 1 < nP) {
            const size_t sn = (size_t)(st + 1) * 64;
#pragma unroll
            for (int j = 0; j < 4; ++j) {
                kr[j] = *(const short8*)(kb + (sn + rr + j * 16) * 3072 + cg * 8);
                vr[j] = *(const short8*)(vtb + (size_t)(rr + j * 16) * TSEQ + sn + cg * 8);
            }
        }
        if (!act) continue;

        // QK^T  (swizzled reads: chunk = (kk*4+quad) ^ (lm&7))
        f32x4 sa[2][4];
#pragma unroll
        for (int mt = 0; mt < 2; ++mt)
#pragma unroll
            for (int nt = 0; nt < 4; ++nt) sa[mt][nt] = zero;
#pragma unroll
        for (int kk = 0; kk < 2; ++kk) {
#pragma unroll
            for (int nt = 0; nt < 4; ++nt) {
                short8 bk = *(const short8*)&Ks[pair][(nt * 16 + lm) * 64 +
                                                     ((((kk << 2) | quad) ^ e) << 3)];
                sa[0][nt] = mfma_bf16(aq[0][kk], bk, sa[0][nt]);
                sa[1][nt] = mfma_bf16(aq[1][kk], bk, sa[1][nt]);
            }
        }

        // softmax (fixed-max) -> per-wave P buffer; band hoisted out
        const int s0 = st * 64;
        if (st != qt) {
            // full tile: no causal mask
#pragma unroll
            for (int mt = 0; mt < 2; ++mt)
#pragma unroll
                for (int nt = 0; nt < 4; ++nt)
#pragma unroll
                    for (int r = 0; r < 4; ++r) {
                        float p = exp2f(0.18033688011112042f * sa[mt][nt][r]);
                        Ps[wave][(mt * 16 + quad * 4 + r) * PLP + nt * 16 + lm] =
                            (short)(__builtin_bit_cast(uint32_t, p) >> 16);
                    }
        } else {
            // band tile: apply causal mask
#pragma unroll
            for (int mt = 0; mt < 2; ++mt) {
                const int qrow = q0 + wv * 32 + mt * 16 + quad * 4;
#pragma unroll
                for (int nt = 0; nt < 4; ++nt) {
                    const int col = s0 + nt * 16 + lm;
#pragma unroll
                    for (int r = 0; r < 4; ++r) {
                        float p = exp2f(0.18033688011112042f * sa[mt][nt][r]);
                        if (col > qrow + r) p = 0.f;
                        Ps[wave][(mt * 16 + quad * 4 + r) * PLP + nt * 16 + lm] =
                            (short)(__builtin_bit_cast(uint32_t, p) >> 16);
                    }
                }
            }
        }

        // P @ V  (+ ones-MFMA accumulates l[q] into lacc)
#pragma unroll
        for (int kk = 0; kk < 2; ++kk) {
            short8 ap0 = *(const short8*)&Ps[wave][lm * PLP + kk * 32 + quad * 8];
            short8 ap1 = *(const short8*)&Ps[wave][(16 + lm) * PLP + kk * 32 + quad * 8];
            lacc[0] = mfma_bf16(ap0, ones8, lacc[0]);
            lacc[1] = mfma_bf16(ap1, ones8, lacc[1]);
#pragma unroll
            for (int t = 0; t < 4; ++t) {
                short8 bv = *(const short8*)&Vts[pair][(t * 16 + lm) * 64 +
                                                       ((((kk << 2) | quad) ^ e) << 3)];
                o_acc[0][t] = mfma_bf16(ap0, bv, o_acc[0][t]);
                o_acc[1][t] = mfma_bf16(ap1, bv, o_acc[1][t]);
            }
        }
    }

    // cross-pair combine through LDS (Ks/Vts/Ps dead after final barrier)
    // lacc[mt][r] already holds the full row-sum (no shuffle reduce needed).
    __syncthreads();
    float* Ob = (float*)&Ks[0][0];    // 64 rows x 64 cols fp32 = 16384B (= Ks)
    float* Lb = (float*)&Ps[0][0];    // 64 floats
    if (pair == 1) {
#pragma unroll
        for (int mt = 0; mt < 2; ++mt)
#pragma unroll
            for (int t = 0; t < 4; ++t)
#pragma unroll
                for (int r = 0; r < 4; ++r)
                    Ob[(wv * 32 + mt * 16 + quad * 4 + r) * 64 + t * 16 + lm] = o_acc[mt][t][r];
        if (lm == 0) {
#pragma unroll
            for (int mt = 0; mt < 2; ++mt)
#pragma unroll
                for (int r = 0; r < 4; ++r)
                    Lb[wv * 32 + mt * 16 + quad * 4 + r] = lacc[mt][r];
        }
    }
    __syncthreads();
    if (pair == 0) {
#pragma unroll
        for (int mt = 0; mt < 2; ++mt) {
#pragma unroll
            for (int r = 0; r < 4; ++r) {
                const int lrow = wv * 32 + mt * 16 + quad * 4 + r;
                float ltot = lacc[mt][r] + Lb[lrow];
                const float inv = 1.0f / ltot;
                const int token = b * TSEQ + q0 + lrow;
#pragma unroll
                for (int t = 0; t < 4; ++t) {
                    float o = o_acc[mt][t][r] + Ob[lrow * 64 + t * 16 + lm];
                    out[(size_t)token * 1024 + h * 64 + t * 16 + lm] = f2bf(o * inv);
                }
            }
        }
    }
}

// ---------------------------------------------------------------------------
// Orchestration
// ---------------------------------------------------------------------------
extern "C" void kernel_launch(void* const* d_in, const int* in_sizes, int n_in,
                              void* d_out, int out_size, void* d_ws, size_t ws_size,
                              hipStream_t stream)
{
    const float* x      = (const float*)d_in[0];
    // d_in[1] = mask (causal, implemented analytically)
    const float* wq     = (const float*)d_in[2];
    const float* wk     = (const float*)d_in[3];
    const float* wv     = (const float*)d_in[4];
    const float* wo     = (const float*)d_in[5];
    const float* w1     = (const float*)d_in[6];
    const float* w2     = (const float*)d_in[7];
    const float* g_attn = (const float*)d_in[8];
    const float* g_ffn  = (const float*)d_in[9];
    float* out = (float*)d_out;

    char* ws = (char*)d_ws;
    const size_t MB = 1024 * 1024;
    short* Wqkv_t = (short*)(ws + 0);
    short* Wo_t   = (short*)(ws + 6 * MB);
    short* W1_t   = (short*)(ws + 8 * MB);
    short* xn     = (short*)(ws + 16 * MB);
    short* hbuf   = (short*)(ws + 24 * MB);
    short* qkv    = (short*)(ws + 32 * MB);
    short* pbufO  = (short*)(ws + 32 * MB);
    short* Vt     = (short*)(ws + 64 * MB);
    float* x2     = (float*)(ws + 64 * MB);
    short* W2_t   = (short*)(ws + 80 * MB);
    short* pbuf2  = (short*)(ws + 0);

    dim3 blk(256);

    transpose_w<<<dim3(16, 16), blk, 0, stream>>>(wq, Wqkv_t, 1024, 1024);
    transpose_w<<<dim3(16, 16), blk, 0, stream>>>(wk, Wqkv_t + (size_t)1024 * 1024, 1024, 1024);
    transpose_w<<<dim3(16, 16), blk, 0, stream>>>(wv, Wqkv_t + (size_t)2048 * 1024, 1024, 1024);
    transpose_w<<<dim3(16, 16), blk, 0, stream>>>(wo, Wo_t, 1024, 1024);
    transpose_w<<<dim3(64, 16), blk, 0, stream>>>(w1, W1_t, 1024, 4096);
    transpose_w<<<dim3(16, 64), blk, 0, stream>>>(w2, W2_t, 4096, 1024);

    rmsnorm_k<<<TOKENS, blk, 0, stream>>>(x, g_attn, xn);

    // qkv = xn @ [Wq|Wk|Wv]   (grid m-fastest)
    gemm_bt<0><<<dim3(TOKENS / 128, 3072 / 128), blk, 0, stream>>>(
        xn, Wqkv_t, qkv, nullptr, TOKENS, 3072, 1024);

    transpose_v<<<dim3(TSEQ / 64, 32), blk, 0, stream>>>(qkv, Vt);

    attn_k<<<dim3(32, TSEQ / 64), dim3(256), 0, stream>>>(qkv, Vt, xn);

    // O-proj split-K=4 (1024 blocks = 4/CU), bf16 partials into dead qkv
    gemm_bt<3><<<dim3(TOKENS / 128, 1024 / 128, 4), blk, 0, stream>>>(
        xn, Wo_t, pbufO, nullptr, TOKENS, 1024, 1024);

    // x2 = x + sum p ; hbuf = rmsnorm(x2)*g_ffn   (fused)
    combine_rms4<<<TOKENS, blk, 0, stream>>>(pbufO, x, g_ffn, x2, hbuf);

    // t = silu(h @ W1)  (into qkv region; pbufO dead)
    gemm_bt<2><<<dim3(TOKENS / 128, HIDDEN / 128), blk, 0, stream>>>(
        hbuf, W1_t, qkv, nullptr, TOKENS, HIDDEN, 1024);

    // FFN2 split-K=4 (1024 blocks = 4/CU), bf16 partials
    gemm_bt<3><<<dim3(TOKENS / 128, 1024 / 128, 4), blk, 0, stream>>>(
        qkv, W2_t, pbuf2, nullptr, TOKENS, 1024, HIDDEN);

    combine_k4<<<dim3(TOKENS * DIM / 4 / 256), blk, 0, stream>>>(
        pbuf2, x2, out, TOKENS * DIM);
}

// Round 12
// 351.313 us; speedup vs baseline: 1.0116x; 1.0116x over previous
//
#include <hip/hip_runtime.h>
#include <hip/hip_bf16.h>
#include <cstdint>
#include <cstddef>

#define DIM    1024
#define NHEAD  16
#define HDIM   64
#define HIDDEN 4096
#define TSEQ   2048
#define TOKENS 4096  // B*T

typedef __attribute__((ext_vector_type(4))) float  f32x4;
typedef __attribute__((ext_vector_type(8))) short  short8;
typedef __attribute__((ext_vector_type(8))) __bf16 bf16x8;

__device__ __forceinline__ short f2bf(float f) {
    union { float f; uint32_t u; } v; v.f = f;
    uint32_t u = v.u;
    uint32_t r = (u + 0x7fffu + ((u >> 16) & 1u)) >> 16;  // RNE
    return (short)r;
}

__device__ __forceinline__ float bf2f(short s) {
    uint32_t u = ((uint32_t)(uint16_t)s) << 16;
    return __builtin_bit_cast(float, u);
}

__device__ __forceinline__ f32x4 mfma_bf16(short8 a, short8 b, f32x4 c) {
    return __builtin_amdgcn_mfma_f32_16x16x32_bf16(
        __builtin_bit_cast(bf16x8, a), __builtin_bit_cast(bf16x8, b), c, 0, 0, 0);
}

// lgkm-only barrier: does NOT drain vmem, keeps register prefetches
// in flight across barriers.
__device__ __forceinline__ void barrier_lds() {
    asm volatile("s_waitcnt lgkmcnt(0)\n\ts_barrier" ::: "memory");
}

// async global -> LDS, 16B per lane. LDS dest is wave-uniform base + lane*16.
__device__ __forceinline__ void glds16(const short* g, short* l) {
    __builtin_amdgcn_global_load_lds(
        (const __attribute__((address_space(1))) void*)g,
        (__attribute__((address_space(3))) void*)l,
        16, 0, 0);
}

#define BARX()  asm volatile("s_barrier" ::: "memory")
#define LGKM0() asm volatile("s_waitcnt lgkmcnt(0)" ::: "memory")

// ---------------------------------------------------------------------------
// Weight transpose + fp32->bf16 convert:  W[K][N] -> Wt[N][K] (bf16)
// ---------------------------------------------------------------------------
__global__ __launch_bounds__(256) void transpose_w(
    const float* __restrict__ W, short* __restrict__ Wt, int K, int N)
{
    __shared__ float tile[64][65];
    const int tid = threadIdx.x;
    const int n0 = blockIdx.x * 64, k0 = blockIdx.y * 64;
    for (int i = tid; i < 4096; i += 256) {
        int r = i >> 6, c = i & 63;
        tile[r][c] = W[(size_t)(k0 + r) * N + n0 + c];
    }
    __syncthreads();
    for (int i = tid; i < 4096; i += 256) {
        int r = i >> 6, c = i & 63;
        Wt[(size_t)(n0 + r) * K + k0 + c] = f2bf(tile[c][r]);
    }
}

// ---------------------------------------------------------------------------
// V transpose: qkv [4096][3072] (V at col 2048 + h*64) -> Vt[bh][64][2048]
// ---------------------------------------------------------------------------
__global__ __launch_bounds__(256) void transpose_v(
    const short* __restrict__ qkv, short* __restrict__ Vt)
{
    __shared__ short tile[64][72];
    const int tid = threadIdx.x;
    const int s0 = blockIdx.x * 64, bh = blockIdx.y;
    const int b = bh >> 4, h = bh & 15;
    const short* src = qkv + ((size_t)(b * TSEQ + s0)) * 3072 + 2048 + h * 64;
    for (int i = tid; i < 512; i += 256) {
        int r = i >> 3, cg = i & 7;
        *(short8*)&tile[r][cg * 8] = *(const short8*)(src + (size_t)r * 3072 + cg * 8);
    }
    __syncthreads();
    short* dst = Vt + ((size_t)bh * 64) * TSEQ + s0;
    for (int i = tid; i < 512; i += 256) {
        int d = i >> 3, sg = i & 7;
        short8 o;
#pragma unroll
        for (int j = 0; j < 8; ++j) o[j] = tile[sg * 8 + j][d];
        *(short8*)(dst + (size_t)d * TSEQ + sg * 8) = o;
    }
}

// ---------------------------------------------------------------------------
// RMSNorm: fp32 in -> bf16 out. One block per token.
// ---------------------------------------------------------------------------
__global__ __launch_bounds__(256) void rmsnorm_k(
    const float* __restrict__ x, const float* __restrict__ g, short* __restrict__ out)
{
    const int t = blockIdx.x, tid = threadIdx.x;
    const int wave = tid >> 6, lane = tid & 63;
    const float4 v = ((const float4*)(x + (size_t)t * DIM))[tid];
    float ss = v.x * v.x + v.y * v.y + v.z * v.z + v.w * v.w;
#pragma unroll
    for (int d = 1; d < 64; d <<= 1) ss += __shfl_xor(ss, d, 64);
    __shared__ float red[4];
    if (lane == 0) red[wave] = ss;
    __syncthreads();
    float tot = red[0] + red[1] + red[2] + red[3];
    float rn = rsqrtf(tot * (1.0f / (float)DIM) + 1e-6f);
    const float4 gv = ((const float4*)g)[tid];
    short4 ov = make_short4(f2bf(v.x * rn * gv.x), f2bf(v.y * rn * gv.y),
                            f2bf(v.z * rn * gv.z), f2bf(v.w * rn * gv.w));
    ((short4*)(out + (size_t)t * DIM))[tid] = ov;
}

// ---------------------------------------------------------------------------
// bf16 GEMM (2-phase, 128x128, BK=64, 4 waves): R5 skeleton, proven best for
// small-K / small-T dispatches (QKV, O-proj, FFN1). Register staging,
// chunk-XOR swizzle -> 0 bank conflicts (R10 PMC-verified).
// EPI: 0 = bf16 out, 1 = fp32 out + fp32 residual, 2 = SiLU -> bf16 out,
//      3 = BF16 partial out at Cout + z*M*N (split-K)
// ---------------------------------------------------------------------------
template <int EPI>
__global__ __launch_bounds__(256) void gemm_bt(
    const short* __restrict__ A, const short* __restrict__ Bt,
    void* __restrict__ Cout, const float* __restrict__ res,
    int M, int N, int K)
{
    __shared__ short As[128 * 64];
    __shared__ short Bs[128 * 64];
    const int tid  = threadIdx.x;
    const int wave = tid >> 6, lane = tid & 63;
    const int lm = lane & 15, quad = lane >> 4;
    const int wm = wave & 1, wn = wave >> 1;
    const int m0 = blockIdx.x * 128, n0 = blockIdx.y * 128;  // m fastest
    const int Ksl = K / gridDim.z;
    const int kbeg = blockIdx.z * Ksl;
    const int nIter = Ksl >> 6;  // >= 4 in all launches here

    const f32x4 zero = {0.f, 0.f, 0.f, 0.f};
    f32x4 acc[4][4];
#pragma unroll
    for (int i = 0; i < 4; ++i)
#pragma unroll
        for (int j = 0; j < 4; ++j) acc[i][j] = zero;

    // staging map: thread t covers rows (t>>3)+j*32, 16B chunk (t&7), j=0..3
    const int srow = tid >> 3;            // 0..31
    const int scol = (tid & 7) * 8;       // shorts
    const int pcol = ((tid & 7) ^ (srow & 7)) * 8;  // XOR-swizzled chunk
    const short* Ap = A + (size_t)(m0 + srow) * K + kbeg + scol;
    const short* Bp = Bt + (size_t)(n0 + srow) * K + kbeg + scol;

    short8 ar[4], br[4];  // one 64-K tile in registers (prefetch)

    auto loadtile = [&]() {
#pragma unroll
        for (int j = 0; j < 4; ++j) {
            ar[j] = *(const short8*)(Ap + (size_t)(j * 32) * K);
            br[j] = *(const short8*)(Bp + (size_t)(j * 32) * K);
        }
        Ap += 64; Bp += 64;
    };

    auto storetile = [&]() {
#pragma unroll
        for (int j = 0; j < 4; ++j) {
            *(short8*)&As[(srow + j * 32) * 64 + pcol] = ar[j];
            *(short8*)&Bs[(srow + j * 32) * 64 + pcol] = br[j];
        }
    };

    const int e = lm & 7;
    auto compute = [&]() {
#pragma unroll
        for (int kk = 0; kk < 2; ++kk) {
            short8 af[4], bf[4];
#pragma unroll
            for (int mt = 0; mt < 4; ++mt)
                af[mt] = *(const short8*)&As[(wm * 64 + mt * 16 + lm) * 64 +
                                             ((((kk << 2) | quad) ^ e) << 3)];
#pragma unroll
            for (int nt = 0; nt < 4; ++nt)
                bf[nt] = *(const short8*)&Bs[(wn * 64 + nt * 16 + lm) * 64 +
                                             ((((kk << 2) | quad) ^ e) << 3)];
#pragma unroll
            for (int mt = 0; mt < 4; ++mt)
#pragma unroll
                for (int nt = 0; nt < 4; ++nt)
                    acc[mt][nt] = mfma_bf16(af[mt], bf[nt], acc[mt][nt]);
        }
    };

    loadtile();  // tile 0 -> regs

    for (int it = 0; it < nIter; ++it) {
        barrier_lds();   // all waves done reading LDS (prev compute)
        storetile();     // regs -> LDS (compiler waits vmcnt on ar/br here)
        barrier_lds();   // tile visible to all waves
        if (it + 1 < nIter) loadtile();  // prefetch next tile (covered by 32 MFMAs)
        compute();
    }

#pragma unroll
    for (int mt = 0; mt < 4; ++mt) {
#pragma unroll
        for (int r = 0; r < 4; ++r) {
            const int row = m0 + wm * 64 + mt * 16 + quad * 4 + r;
#pragma unroll
            for (int nt = 0; nt < 4; ++nt) {
                const int col = n0 + wn * 64 + nt * 16 + lm;
                const size_t idx = (size_t)row * N + col;
                const float v = acc[mt][nt][r];
                if constexpr (EPI == 0) {
                    ((short*)Cout)[idx] = f2bf(v);
                } else if constexpr (EPI == 1) {
                    ((float*)Cout)[idx] = res[idx] + v;
                } else if constexpr (EPI == 2) {
                    ((short*)Cout)[idx] = f2bf(v / (1.0f + __expf(-v)));
                } else {
                    ((short*)Cout)[(size_t)blockIdx.z * M * N + idx] = f2bf(v);
                }
            }
        }
    }
}

// ---------------------------------------------------------------------------
// bf16 GEMM (8-phase, 256x256, BK=64, 8 waves): R6 kernel, correctness-
// proven (R6 run passed on all gemms). Used ONLY for FFN2 (K-slice 1024,
// T=16): in R6's profile FFN2 ran <=51.4us under this schedule vs 67.9us
// under the 2-phase (R10 PMC) — deep-K is the 8-phase regime; small-T
// dispatches (QKV/O-proj) regressed under it, so they stay 2-phase.
// Counted vmcnt(4) once per K-tile, never 0 mid-loop; stage slots race-free
// by region death; chunk-XOR swizzle via pre-swizzled global source.
// ---------------------------------------------------------------------------
template <int EPI>
__global__ __launch_bounds__(512, 2) void gemm8_bt(
    const short* __restrict__ A, const short* __restrict__ Bt,
    void* __restrict__ Cout, const float* __restrict__ res,
    int M, int N, int K)
{
    __shared__ short As[2][256 * 64];   // 64 KB
    __shared__ short Bs[2][256 * 64];   // 64 KB
    const int tid  = threadIdx.x;
    const int wave = tid >> 6, lane = tid & 63;
    const int lm = lane & 15, quad = lane >> 4;
    const int ex = lm & 7;
    const int wm = wave & 1, wn = wave >> 1;
    const int m0 = blockIdx.x * 256, n0 = blockIdx.y * 256;  // m fastest
    const int Ksl = K / gridDim.z;
    const int kbeg = blockIdx.z * Ksl;
    const int T = Ksl >> 6;  // #K-tiles

    const f32x4 zero = {0.f, 0.f, 0.f, 0.f};
    f32x4 acc[8][4];
#pragma unroll
    for (int i = 0; i < 8; ++i)
#pragma unroll
        for (int j = 0; j < 4; ++j) acc[i][j] = zero;

    const int srow = wave * 8 + (lane >> 3);
    const int scol = ((lane & 7) ^ ((lane >> 3) & 7)) * 8;
    const short* ApS = A + (size_t)(m0 + srow) * K + kbeg + scol;
    const short* BpS = Bt + (size_t)(n0 + srow) * K + kbeg + scol;

    auto stageA = [&](int buf) {
#pragma unroll
        for (int j = 0; j < 4; ++j)
            glds16(ApS + (size_t)(j * 64) * K, &As[buf][(j * 64 + wave * 8) * 64]);
        ApS += 64;
    };
    auto stageB = [&](int buf) {
#pragma unroll
        for (int j = 0; j < 4; ++j)
            glds16(BpS + (size_t)(j * 64) * K, &Bs[buf][(j * 64 + wave * 8) * 64]);
        BpS += 64;
    };

#define READ_A(buf, kk) do { _Pragma("unroll") \
    for (int mt = 0; mt < 8; ++mt) \
        af[mt] = *(const short8*)&As[buf][(wm * 128 + mt * 16 + lm) * 64 + \
                                          ((((kk) << 2) | quad) ^ ex) * 8]; } while (0)
#define READ_B(buf, kk, np) do { _Pragma("unroll") \
    for (int j = 0; j < 2; ++j) \
        bfp[j] = *(const short8*)&Bs[buf][(wn * 64 + ((np) * 2 + j) * 16 + lm) * 64 + \
                                          ((((kk) << 2) | quad) ^ ex) * 8]; } while (0)
#define MFMA16(np) do { _Pragma("unroll") \
    for (int mt = 0; mt < 8; ++mt) { \
        acc[mt][(np) * 2 + 0] = mfma_bf16(af[mt], bfp[0], acc[mt][(np) * 2 + 0]); \
        acc[mt][(np) * 2 + 1] = mfma_bf16(af[mt], bfp[1], acc[mt][(np) * 2 + 1]); \
    } } while (0)

    // prologue: tile0 (A+B) + tile1 (A); wait tile0, leave A(1) in flight
    stageA(0); stageB(0); stageA(1);
    asm volatile("s_waitcnt vmcnt(4)" ::: "memory");
    BARX();

    for (int t = 0; t < T; ++t) {
        const int buf = t & 1;
        short8 af[8], bfp[2];
        // ---- P0: A kk0 (8 reads) + B01 kk0 (2) ; stage B(t+1)
        READ_A(buf, 0); READ_B(buf, 0, 0);
        if (t + 1 < T) stageB(buf ^ 1);
        BARX(); LGKM0();
        __builtin_amdgcn_s_setprio(1); MFMA16(0); __builtin_amdgcn_s_setprio(0);
        BARX();
        // ---- P1: B23 kk0 (2 reads)
        READ_B(buf, 0, 1);
        BARX(); LGKM0();
        __builtin_amdgcn_s_setprio(1); MFMA16(1); __builtin_amdgcn_s_setprio(0);
        BARX();
        // ---- P2: A kk1 (8) + B01 kk1 (2)
        READ_A(buf, 1); READ_B(buf, 1, 0);
        BARX(); LGKM0();
        __builtin_amdgcn_s_setprio(1); MFMA16(0); __builtin_amdgcn_s_setprio(0);
        BARX();
        // ---- P3: B23 kk1 (2) ; stage A(t+2) ; counted vmcnt
        READ_B(buf, 1, 1);
        if (t + 2 < T) stageA(buf);
        BARX(); LGKM0();
        __builtin_amdgcn_s_setprio(1); MFMA16(1); __builtin_amdgcn_s_setprio(0);
        if (t + 2 < T) { asm volatile("s_waitcnt vmcnt(4)" ::: "memory"); }
        else           { asm volatile("s_waitcnt vmcnt(0)" ::: "memory"); }
        BARX();
    }
#undef READ_A
#undef READ_B
#undef MFMA16

#pragma unroll
    for (int mt = 0; mt < 8; ++mt) {
#pragma unroll
        for (int r = 0; r < 4; ++r) {
            const int row = m0 + wm * 128 + mt * 16 + quad * 4 + r;
#pragma unroll
            for (int nt = 0; nt < 4; ++nt) {
                const int col = n0 + wn * 64 + nt * 16 + lm;
                const size_t idx = (size_t)row * N + col;
                const float v = acc[mt][nt][r];
                if constexpr (EPI == 0) {
                    ((short*)Cout)[idx] = f2bf(v);
                } else if constexpr (EPI == 1) {
                    ((float*)Cout)[idx] = res[idx] + v;
                } else if constexpr (EPI == 2) {
                    ((short*)Cout)[idx] = f2bf(v / (1.0f + __expf(-v)));
                } else {
                    ((short*)Cout)[(size_t)blockIdx.z * M * N + idx] = f2bf(v);
                }
            }
        }
    }
}

// ---------------------------------------------------------------------------
// Split-K combine (4 bf16 partials): out = res + sum_{s<4} p[s]
// ---------------------------------------------------------------------------
__global__ __launch_bounds__(256) void combine_k4(
    const short* __restrict__ p, const float* __restrict__ res,
    float* __restrict__ out, int n)
{
    const int i = blockIdx.x * 256 + threadIdx.x;
    if (i * 4 < n) {
        float4 v = ((const float4*)res)[i];
#pragma unroll
        for (int s = 0; s < 4; ++s) {
            short4 ps = ((const short4*)(p + (size_t)s * n))[i];
            v.x += bf2f(ps.x); v.y += bf2f(ps.y);
            v.z += bf2f(ps.z); v.w += bf2f(ps.w);
        }
        ((float4*)out)[i] = v;
    }
}

// ---------------------------------------------------------------------------
// Fused split-K combine (4 bf16 partials) + RMSNorm: one block per token.
// ---------------------------------------------------------------------------
__global__ __launch_bounds__(256) void combine_rms4(
    const short* __restrict__ p, const float* __restrict__ res,
    const float* __restrict__ g, float* __restrict__ x2out,
    short* __restrict__ nout)
{
    const int t = blockIdx.x, tid = threadIdx.x;
    const int wave = tid >> 6, lane = tid & 63;
    const size_t i4 = (size_t)t * 256 + tid;  // float4 index
    float4 v = ((const float4*)res)[i4];
#pragma unroll
    for (int s = 0; s < 4; ++s) {
        short4 ps = ((const short4*)(p + (size_t)s * TOKENS * DIM))[i4];
        v.x += bf2f(ps.x); v.y += bf2f(ps.y);
        v.z += bf2f(ps.z); v.w += bf2f(ps.w);
    }
    ((float4*)x2out)[i4] = v;
    float ss = v.x * v.x + v.y * v.y + v.z * v.z + v.w * v.w;
#pragma unroll
    for (int d = 1; d < 64; d <<= 1) ss += __shfl_xor(ss, d, 64);
    __shared__ float red[4];
    if (lane == 0) red[wave] = ss;
    __syncthreads();
    float tot = red[0] + red[1] + red[2] + red[3];
    float rn = rsqrtf(tot * (1.0f / (float)DIM) + 1e-6f);
    const float4 gv = ((const float4*)g)[tid];
    short4 ov = make_short4(f2bf(v.x * rn * gv.x), f2bf(v.y * rn * gv.y),
                            f2bf(v.z * rn * gv.z), f2bf(v.w * rn * gv.w));
    ((short4*)nout)[i4] = ov;
}

// ---------------------------------------------------------------------------
// Flash attention, causal, fixed-max softmax. (R10, unchanged this round.)
// K/V swizzled (free addressing, 0-conflict b128); P padded LP=72 (cheap
// scalar writes); lsum via ones-MFMA; band-hoisted softmax.
// ---------------------------------------------------------------------------
#define PLP 72
__global__ __launch_bounds__(256, 2) void attn_k(
    const short* __restrict__ qkv, const short* __restrict__ Vt,
    short* __restrict__ out)
{
    __shared__ short Ks[2][64 * 64];    // 16 KB (swizzled)
    __shared__ short Vts[2][64 * 64];   // 16 KB (swizzled)
    __shared__ short Ps[4][32 * PLP];   // 18 KB (padded, plain addressing)

    const int tid = threadIdx.x, wave = tid >> 6, lane = tid & 63;
    const int pair = wave >> 1, wv = wave & 1;
    const int lm = lane & 15, quad = lane >> 4;
    const int e = lm & 7;
    const int bh = blockIdx.x;
    const int qt = (gridDim.y - 1) - blockIdx.y;  // heavy blocks first
    const int b = bh >> 4, h = bh & 15;
    const int q0 = qt * 64;

    const int n  = qt + 1;           // total s-tiles
    const int nA = (n + 1) >> 1;     // tiles for pair A
    const int nP = pair ? (n >> 1) : nA;
    const int sbase = pair ? nA : 0;

    const int tp = tid & 127;        // thread index within pair
    const int rr = tp >> 3, cg = tp & 7;
    const int pcol = (cg ^ (rr & 7)) * 8;   // XOR-swizzled chunk (K/V staging)

    // Q fragments (loop-invariant, direct to registers)
    const short* qb = qkv + ((size_t)(b * TSEQ + q0)) * 3072 + h * 64;
    short8 aq[2][2];
#pragma unroll
    for (int mt = 0; mt < 2; ++mt)
#pragma unroll
        for (int kk = 0; kk < 2; ++kk)
            aq[mt][kk] = *(const short8*)(qb + (size_t)(wv * 32 + mt * 16 + lm) * 3072 + kk * 32 + quad * 8);

    const short* kb  = qkv + (size_t)b * TSEQ * 3072 + 1024 + h * 64;
    const short* vtb = Vt + (size_t)bh * 64 * TSEQ;

    const short ONEBF = (short)0x3F80;  // bf16 1.0
    const short8 ones8 = {ONEBF, ONEBF, ONEBF, ONEBF, ONEBF, ONEBF, ONEBF, ONEBF};

    const f32x4 zero = {0.f, 0.f, 0.f, 0.f};
    f32x4 o_acc[2][4];
    f32x4 lacc[2];  // l[q] per mt
#pragma unroll
    for (int mt = 0; mt < 2; ++mt) {
#pragma unroll
        for (int t = 0; t < 4; ++t) o_acc[mt][t] = zero;
        lacc[mt] = zero;
    }

    // initial register prefetch of this pair's first tile
    short8 kr[4], vr[4];
    if (nP > 0) {
        const size_t s0i = (size_t)sbase * 64;
#pragma unroll
        for (int j = 0; j < 4; ++j) {
            kr[j] = *(const short8*)(kb + (s0i + rr + j * 16) * 3072 + cg * 8);
            vr[j] = *(const short8*)(vtb + (size_t)(rr + j * 16) * TSEQ + s0i + cg * 8);
        }
    }

    for (int it = 0; it < nA; ++it) {
        const int st = sbase + it;
        const bool act = it < nP;
        __syncthreads();
        if (act) {
#pragma unroll
            for (int j = 0; j < 4; ++j) {
                *(short8*)&Ks[pair][(rr + j * 16) * 64 + pcol] = kr[j];
                *(short8*)&Vts[pair][(rr + j * 16) * 64 + pcol] = vr[j];
            }
        }
        __syncthreads();
        if (act && it + 1 < nP) {
            const size_t sn = (size_t)(st + 1) * 64;
#pragma unroll
            for (int j = 0; j < 4; ++j) {
                kr[j] = *(const short8*)(kb + (sn + rr + j * 16) * 3072 + cg * 8);
                vr[j] = *(const short8*)(vtb + (size_t)(rr + j * 16) * TSEQ + sn + cg * 8);
            }
        }
        if (!act) continue;

        // QK^T  (swizzled reads: chunk = (kk*4+quad) ^ (lm&7))
        f32x4 sa[2][4];
#pragma unroll
        for (int mt = 0; mt < 2; ++mt)
#pragma unroll
            for (int nt = 0; nt < 4; ++nt) sa[mt][nt] = zero;
#pragma unroll
        for (int kk = 0; kk < 2; ++kk) {
#pragma unroll
            for (int nt = 0; nt < 4; ++nt) {
                short8 bk = *(const short8*)&Ks[pair][(nt * 16 + lm) * 64 +
                                                     ((((kk << 2) | quad) ^ e) << 3)];
                sa[0][nt] = mfma_bf16(aq[0][kk], bk, sa[0][nt]);
                sa[1][nt] = mfma_bf16(aq[1][kk], bk, sa[1][nt]);
            }
        }

        // softmax (fixed-max) -> per-wave P buffer; band hoisted out
        const int s0 = st * 64;
        if (st != qt) {
#pragma unroll
            for (int mt = 0; mt < 2; ++mt)
#pragma unroll
                for (int nt = 0; nt < 4; ++nt)
#pragma unroll
                    for (int r = 0; r < 4; ++r) {
                        float p = exp2f(0.18033688011112042f * sa[mt][nt][r]);
                        Ps[wave][(mt * 16 + quad * 4 + r) * PLP + nt * 16 + lm] =
                            (short)(__builtin_bit_cast(uint32_t, p) >> 16);
                    }
        } else {
#pragma unroll
            for (int mt = 0; mt < 2; ++mt) {
                const int qrow = q0 + wv * 32 + mt * 16 + quad * 4;
#pragma unroll
                for (int nt = 0; nt < 4; ++nt) {
                    const int col = s0 + nt * 16 + lm;
#pragma unroll
                    for (int r = 0; r < 4; ++r) {
                        float p = exp2f(0.18033688011112042f * sa[mt][nt][r]);
                        if (col > qrow + r) p = 0.f;
                        Ps[wave][(mt * 16 + quad * 4 + r) * PLP + nt * 16 + lm] =
                            (short)(__builtin_bit_cast(uint32_t, p) >> 16);
                    }
                }
            }
        }

        // P @ V  (+ ones-MFMA accumulates l[q] into lacc)
#pragma unroll
        for (int kk = 0; kk < 2; ++kk) {
            short8 ap0 = *(const short8*)&Ps[wave][lm * PLP + kk * 32 + quad * 8];
            short8 ap1 = *(const short8*)&Ps[wave][(16 + lm) * PLP + kk * 32 + quad * 8];
            lacc[0] = mfma_bf16(ap0, ones8, lacc[0]);
            lacc[1] = mfma_bf16(ap1, ones8, lacc[1]);
#pragma unroll
            for (int t = 0; t < 4; ++t) {
                short8 bv = *(const short8*)&Vts[pair][(t * 16 + lm) * 64 +
                                                       ((((kk << 2) | quad) ^ e) << 3)];
                o_acc[0][t] = mfma_bf16(ap0, bv, o_acc[0][t]);
                o_acc[1][t] = mfma_bf16(ap1, bv, o_acc[1][t]);
            }
        }
    }

    // cross-pair combine through LDS (Ks/Vts/Ps dead after final barrier)
    __syncthreads();
    float* Ob = (float*)&Ks[0][0];    // 64 rows x 64 cols fp32 = 16384B (= Ks)
    float* Lb = (float*)&Ps[0][0];    // 64 floats
    if (pair == 1) {
#pragma unroll
        for (int mt = 0; mt < 2; ++mt)
#pragma unroll
            for (int t = 0; t < 4; ++t)
#pragma unroll
                for (int r = 0; r < 4; ++r)
                    Ob[(wv * 32 + mt * 16 + quad * 4 + r) * 64 + t * 16 + lm] = o_acc[mt][t][r];
        if (lm == 0) {
#pragma unroll
            for (int mt = 0; mt < 2; ++mt)
#pragma unroll
                for (int r = 0; r < 4; ++r)
                    Lb[wv * 32 + mt * 16 + quad * 4 + r] = lacc[mt][r];
        }
    }
    __syncthreads();
    if (pair == 0) {
#pragma unroll
        for (int mt = 0; mt < 2; ++mt) {
#pragma unroll
            for (int r = 0; r < 4; ++r) {
                const int lrow = wv * 32 + mt * 16 + quad * 4 + r;
                float ltot = lacc[mt][r] + Lb[lrow];
                const float inv = 1.0f / ltot;
                const int token = b * TSEQ + q0 + lrow;
#pragma unroll
                for (int t = 0; t < 4; ++t) {
                    float o = o_acc[mt][t][r] + Ob[lrow * 64 + t * 16 + lm];
                    out[(size_t)token * 1024 + h * 64 + t * 16 + lm] = f2bf(o * inv);
                }
            }
        }
    }
}

// ---------------------------------------------------------------------------
// Orchestration
// ---------------------------------------------------------------------------
extern "C" void kernel_launch(void* const* d_in, const int* in_sizes, int n_in,
                              void* d_out, int out_size, void* d_ws, size_t ws_size,
                              hipStream_t stream)
{
    const float* x      = (const float*)d_in[0];
    // d_in[1] = mask (causal, implemented analytically)
    const float* wq     = (const float*)d_in[2];
    const float* wk     = (const float*)d_in[3];
    const float* wv     = (const float*)d_in[4];
    const float* wo     = (const float*)d_in[5];
    const float* w1     = (const float*)d_in[6];
    const float* w2     = (const float*)d_in[7];
    const float* g_attn = (const float*)d_in[8];
    const float* g_ffn  = (const float*)d_in[9];
    float* out = (float*)d_out;

    char* ws = (char*)d_ws;
    const size_t MB = 1024 * 1024;
    short* Wqkv_t = (short*)(ws + 0);
    short* Wo_t   = (short*)(ws + 6 * MB);
    short* W1_t   = (short*)(ws + 8 * MB);
    short* xn     = (short*)(ws + 16 * MB);
    short* hbuf   = (short*)(ws + 24 * MB);
    short* qkv    = (short*)(ws + 32 * MB);
    short* pbufO  = (short*)(ws + 32 * MB);
    short* Vt     = (short*)(ws + 64 * MB);
    float* x2     = (float*)(ws + 64 * MB);
    short* W2_t   = (short*)(ws + 80 * MB);
    short* pbuf2  = (short*)(ws + 0);

    dim3 blk(256);

    transpose_w<<<dim3(16, 16), blk, 0, stream>>>(wq, Wqkv_t, 1024, 1024);
    transpose_w<<<dim3(16, 16), blk, 0, stream>>>(wk, Wqkv_t + (size_t)1024 * 1024, 1024, 1024);
    transpose_w<<<dim3(16, 16), blk, 0, stream>>>(wv, Wqkv_t + (size_t)2048 * 1024, 1024, 1024);
    transpose_w<<<dim3(16, 16), blk, 0, stream>>>(wo, Wo_t, 1024, 1024);
    transpose_w<<<dim3(64, 16), blk, 0, stream>>>(w1, W1_t, 1024, 4096);
    transpose_w<<<dim3(16, 64), blk, 0, stream>>>(w2, W2_t, 4096, 1024);

    rmsnorm_k<<<TOKENS, blk, 0, stream>>>(x, g_attn, xn);

    // qkv = xn @ [Wq|Wk|Wv]   (grid m-fastest, 2-phase)
    gemm_bt<0><<<dim3(TOKENS / 128, 3072 / 128), blk, 0, stream>>>(
        xn, Wqkv_t, qkv, nullptr, TOKENS, 3072, 1024);

    transpose_v<<<dim3(TSEQ / 64, 32), blk, 0, stream>>>(qkv, Vt);

    attn_k<<<dim3(32, TSEQ / 64), dim3(256), 0, stream>>>(qkv, Vt, xn);

    // O-proj split-K=4 (2-phase), bf16 partials into dead qkv
    gemm_bt<3><<<dim3(TOKENS / 128, 1024 / 128, 4), blk, 0, stream>>>(
        xn, Wo_t, pbufO, nullptr, TOKENS, 1024, 1024);

    // x2 = x + sum p ; hbuf = rmsnorm(x2)*g_ffn   (fused)
    combine_rms4<<<TOKENS, blk, 0, stream>>>(pbufO, x, g_ffn, x2, hbuf);

    // t = silu(h @ W1)  (2-phase)
    gemm_bt<2><<<dim3(TOKENS / 128, HIDDEN / 128), blk, 0, stream>>>(
        hbuf, W1_t, qkv, nullptr, TOKENS, HIDDEN, 1024);

    // FFN2 split-K=4: 8-phase 256^2 (deep-K regime; <=51us in R6 profile
    // vs 67.9us 2-phase in R10), bf16 partials
    gemm8_bt<3><<<dim3(TOKENS / 256, 1024 / 256, 4), dim3(512), 0, stream>>>(
        qkv, W2_t, pbuf2, nullptr, TOKENS, 1024, HIDDEN);

    combine_k4<<<dim3(TOKENS * DIM / 4 / 256), blk, 0, stream>>>(
        pbuf2, x2, out, TOKENS * DIM);
}

// Round 13
// 349.692 us; speedup vs baseline: 1.0163x; 1.0046x over previous
//
#include <hip/hip_runtime.h>
#include <hip/hip_bf16.h>
#include <cstdint>
#include <cstddef>

#define DIM    1024
#define NHEAD  16
#define HDIM   64
#define HIDDEN 4096
#define TSEQ   2048
#define TOKENS 4096  // B*T

typedef __attribute__((ext_vector_type(4))) float  f32x4;
typedef __attribute__((ext_vector_type(8))) short  short8;
typedef __attribute__((ext_vector_type(8))) __bf16 bf16x8;

__device__ __forceinline__ short f2bf(float f) {
    union { float f; uint32_t u; } v; v.f = f;
    uint32_t u = v.u;
    uint32_t r = (u + 0x7fffu + ((u >> 16) & 1u)) >> 16;  // RNE
    return (short)r;
}

__device__ __forceinline__ float bf2f(short s) {
    uint32_t u = ((uint32_t)(uint16_t)s) << 16;
    return __builtin_bit_cast(float, u);
}

__device__ __forceinline__ f32x4 mfma_bf16(short8 a, short8 b, f32x4 c) {
    return __builtin_amdgcn_mfma_f32_16x16x32_bf16(
        __builtin_bit_cast(bf16x8, a), __builtin_bit_cast(bf16x8, b), c, 0, 0, 0);
}

// lgkm-only barrier: does NOT drain vmem, keeps register prefetches
// in flight across barriers.
__device__ __forceinline__ void barrier_lds() {
    asm volatile("s_waitcnt lgkmcnt(0)\n\ts_barrier" ::: "memory");
}

// async global -> LDS, 16B per lane. LDS dest is wave-uniform base + lane*16.
__device__ __forceinline__ void glds16(const short* g, short* l) {
    __builtin_amdgcn_global_load_lds(
        (const __attribute__((address_space(1))) void*)g,
        (__attribute__((address_space(3))) void*)l,
        16, 0, 0);
}

#define BARX()  asm volatile("s_barrier" ::: "memory")
#define LGKM0() asm volatile("s_waitcnt lgkmcnt(0)" ::: "memory")

// ---------------------------------------------------------------------------
// Weight transpose + fp32->bf16 convert:  W[K][N] -> Wt[N][K] (bf16)
// ---------------------------------------------------------------------------
__global__ __launch_bounds__(256) void transpose_w(
    const float* __restrict__ W, short* __restrict__ Wt, int K, int N)
{
    __shared__ float tile[64][65];
    const int tid = threadIdx.x;
    const int n0 = blockIdx.x * 64, k0 = blockIdx.y * 64;
    for (int i = tid; i < 4096; i += 256) {
        int r = i >> 6, c = i & 63;
        tile[r][c] = W[(size_t)(k0 + r) * N + n0 + c];
    }
    __syncthreads();
    for (int i = tid; i < 4096; i += 256) {
        int r = i >> 6, c = i & 63;
        Wt[(size_t)(n0 + r) * K + k0 + c] = f2bf(tile[c][r]);
    }
}

// ---------------------------------------------------------------------------
// V transpose: qkv [4096][3072] (V at col 2048 + h*64) -> Vt[bh][64][2048]
// ---------------------------------------------------------------------------
__global__ __launch_bounds__(256) void transpose_v(
    const short* __restrict__ qkv, short* __restrict__ Vt)
{
    __shared__ short tile[64][72];
    const int tid = threadIdx.x;
    const int s0 = blockIdx.x * 64, bh = blockIdx.y;
    const int b = bh >> 4, h = bh & 15;
    const short* src = qkv + ((size_t)(b * TSEQ + s0)) * 3072 + 2048 + h * 64;
    for (int i = tid; i < 512; i += 256) {
        int r = i >> 3, cg = i & 7;
        *(short8*)&tile[r][cg * 8] = *(const short8*)(src + (size_t)r * 3072 + cg * 8);
    }
    __syncthreads();
    short* dst = Vt + ((size_t)bh * 64) * TSEQ + s0;
    for (int i = tid; i < 512; i += 256) {
        int d = i >> 3, sg = i & 7;
        short8 o;
#pragma unroll
        for (int j = 0; j < 8; ++j) o[j] = tile[sg * 8 + j][d];
        *(short8*)(dst + (size_t)d * TSEQ + sg * 8) = o;
    }
}

// ---------------------------------------------------------------------------
// RMSNorm: fp32 in -> bf16 out. One block per token.
// ---------------------------------------------------------------------------
__global__ __launch_bounds__(256) void rmsnorm_k(
    const float* __restrict__ x, const float* __restrict__ g, short* __restrict__ out)
{
    const int t = blockIdx.x, tid = threadIdx.x;
    const int wave = tid >> 6, lane = tid & 63;
    const float4 v = ((const float4*)(x + (size_t)t * DIM))[tid];
    float ss = v.x * v.x + v.y * v.y + v.z * v.z + v.w * v.w;
#pragma unroll
    for (int d = 1; d < 64; d <<= 1) ss += __shfl_xor(ss, d, 64);
    __shared__ float red[4];
    if (lane == 0) red[wave] = ss;
    __syncthreads();
    float tot = red[0] + red[1] + red[2] + red[3];
    float rn = rsqrtf(tot * (1.0f / (float)DIM) + 1e-6f);
    const float4 gv = ((const float4*)g)[tid];
    short4 ov = make_short4(f2bf(v.x * rn * gv.x), f2bf(v.y * rn * gv.y),
                            f2bf(v.z * rn * gv.z), f2bf(v.w * rn * gv.w));
    ((short4*)(out + (size_t)t * DIM))[tid] = ov;
}

// ---------------------------------------------------------------------------
// bf16 GEMM (2-phase, 128x128, BK=64, 4 waves): R5 skeleton, proven best for
// small-K / small-T dispatches (QKV at 768 blocks, O-proj at T=4).
// Register staging, chunk-XOR swizzle -> 0 bank conflicts (R10 PMC).
// EPI: 0 = bf16 out, 1 = fp32 out + fp32 residual, 2 = SiLU -> bf16 out,
//      3 = BF16 partial out at Cout + z*M*N (split-K)
// ---------------------------------------------------------------------------
template <int EPI>
__global__ __launch_bounds__(256) void gemm_bt(
    const short* __restrict__ A, const short* __restrict__ Bt,
    void* __restrict__ Cout, const float* __restrict__ res,
    int M, int N, int K)
{
    __shared__ short As[128 * 64];
    __shared__ short Bs[128 * 64];
    const int tid  = threadIdx.x;
    const int wave = tid >> 6, lane = tid & 63;
    const int lm = lane & 15, quad = lane >> 4;
    const int wm = wave & 1, wn = wave >> 1;
    const int m0 = blockIdx.x * 128, n0 = blockIdx.y * 128;  // m fastest
    const int Ksl = K / gridDim.z;
    const int kbeg = blockIdx.z * Ksl;
    const int nIter = Ksl >> 6;  // >= 4 in all launches here

    const f32x4 zero = {0.f, 0.f, 0.f, 0.f};
    f32x4 acc[4][4];
#pragma unroll
    for (int i = 0; i < 4; ++i)
#pragma unroll
        for (int j = 0; j < 4; ++j) acc[i][j] = zero;

    // staging map: thread t covers rows (t>>3)+j*32, 16B chunk (t&7), j=0..3
    const int srow = tid >> 3;            // 0..31
    const int scol = (tid & 7) * 8;       // shorts
    const int pcol = ((tid & 7) ^ (srow & 7)) * 8;  // XOR-swizzled chunk
    const short* Ap = A + (size_t)(m0 + srow) * K + kbeg + scol;
    const short* Bp = Bt + (size_t)(n0 + srow) * K + kbeg + scol;

    short8 ar[4], br[4];  // one 64-K tile in registers (prefetch)

    auto loadtile = [&]() {
#pragma unroll
        for (int j = 0; j < 4; ++j) {
            ar[j] = *(const short8*)(Ap + (size_t)(j * 32) * K);
            br[j] = *(const short8*)(Bp + (size_t)(j * 32) * K);
        }
        Ap += 64; Bp += 64;
    };

    auto storetile = [&]() {
#pragma unroll
        for (int j = 0; j < 4; ++j) {
            *(short8*)&As[(srow + j * 32) * 64 + pcol] = ar[j];
            *(short8*)&Bs[(srow + j * 32) * 64 + pcol] = br[j];
        }
    };

    const int e = lm & 7;
    auto compute = [&]() {
#pragma unroll
        for (int kk = 0; kk < 2; ++kk) {
            short8 af[4], bf[4];
#pragma unroll
            for (int mt = 0; mt < 4; ++mt)
                af[mt] = *(const short8*)&As[(wm * 64 + mt * 16 + lm) * 64 +
                                             ((((kk << 2) | quad) ^ e) << 3)];
#pragma unroll
            for (int nt = 0; nt < 4; ++nt)
                bf[nt] = *(const short8*)&Bs[(wn * 64 + nt * 16 + lm) * 64 +
                                             ((((kk << 2) | quad) ^ e) << 3)];
#pragma unroll
            for (int mt = 0; mt < 4; ++mt)
#pragma unroll
                for (int nt = 0; nt < 4; ++nt)
                    acc[mt][nt] = mfma_bf16(af[mt], bf[nt], acc[mt][nt]);
        }
    };

    loadtile();  // tile 0 -> regs

    for (int it = 0; it < nIter; ++it) {
        barrier_lds();   // all waves done reading LDS (prev compute)
        storetile();     // regs -> LDS (compiler waits vmcnt on ar/br here)
        barrier_lds();   // tile visible to all waves
        if (it + 1 < nIter) loadtile();  // prefetch next tile (covered by 32 MFMAs)
        compute();
    }

#pragma unroll
    for (int mt = 0; mt < 4; ++mt) {
#pragma unroll
        for (int r = 0; r < 4; ++r) {
            const int row = m0 + wm * 64 + mt * 16 + quad * 4 + r;
#pragma unroll
            for (int nt = 0; nt < 4; ++nt) {
                const int col = n0 + wn * 64 + nt * 16 + lm;
                const size_t idx = (size_t)row * N + col;
                const float v = acc[mt][nt][r];
                if constexpr (EPI == 0) {
                    ((short*)Cout)[idx] = f2bf(v);
                } else if constexpr (EPI == 1) {
                    ((float*)Cout)[idx] = res[idx] + v;
                } else if constexpr (EPI == 2) {
                    ((short*)Cout)[idx] = f2bf(v / (1.0f + __expf(-v)));
                } else {
                    ((short*)Cout)[(size_t)blockIdx.z * M * N + idx] = f2bf(v);
                }
            }
        }
    }
}

// ---------------------------------------------------------------------------
// bf16 GEMM (8-phase, 256x256, BK=64, 8 waves): R6 kernel, correctness-
// proven. Deep-K regime: 256 blocks (1/CU) x T=16. Used for FFN2 (R11:
// 67.9 -> <52us) and, this round, FFN1 (identical per-block geometry:
// 256 blocks, Ksl=1024, T=16). QKV (768 blocks) and O-proj (T=4) stay
// 2-phase (R6 showed they regress under this schedule).
// Counted vmcnt(4) once per K-tile, never 0 mid-loop; stage slots race-free
// by region death; chunk-XOR swizzle via pre-swizzled global source.
// ---------------------------------------------------------------------------
template <int EPI>
__global__ __launch_bounds__(512, 2) void gemm8_bt(
    const short* __restrict__ A, const short* __restrict__ Bt,
    void* __restrict__ Cout, const float* __restrict__ res,
    int M, int N, int K)
{
    __shared__ short As[2][256 * 64];   // 64 KB
    __shared__ short Bs[2][256 * 64];   // 64 KB
    const int tid  = threadIdx.x;
    const int wave = tid >> 6, lane = tid & 63;
    const int lm = lane & 15, quad = lane >> 4;
    const int ex = lm & 7;
    const int wm = wave & 1, wn = wave >> 1;
    const int m0 = blockIdx.x * 256, n0 = blockIdx.y * 256;  // m fastest
    const int Ksl = K / gridDim.z;
    const int kbeg = blockIdx.z * Ksl;
    const int T = Ksl >> 6;  // #K-tiles

    const f32x4 zero = {0.f, 0.f, 0.f, 0.f};
    f32x4 acc[8][4];
#pragma unroll
    for (int i = 0; i < 8; ++i)
#pragma unroll
        for (int j = 0; j < 4; ++j) acc[i][j] = zero;

    const int srow = wave * 8 + (lane >> 3);
    const int scol = ((lane & 7) ^ ((lane >> 3) & 7)) * 8;
    const short* ApS = A + (size_t)(m0 + srow) * K + kbeg + scol;
    const short* BpS = Bt + (size_t)(n0 + srow) * K + kbeg + scol;

    auto stageA = [&](int buf) {
#pragma unroll
        for (int j = 0; j < 4; ++j)
            glds16(ApS + (size_t)(j * 64) * K, &As[buf][(j * 64 + wave * 8) * 64]);
        ApS += 64;
    };
    auto stageB = [&](int buf) {
#pragma unroll
        for (int j = 0; j < 4; ++j)
            glds16(BpS + (size_t)(j * 64) * K, &Bs[buf][(j * 64 + wave * 8) * 64]);
        BpS += 64;
    };

#define READ_A(buf, kk) do { _Pragma("unroll") \
    for (int mt = 0; mt < 8; ++mt) \
        af[mt] = *(const short8*)&As[buf][(wm * 128 + mt * 16 + lm) * 64 + \
                                          ((((kk) << 2) | quad) ^ ex) * 8]; } while (0)
#define READ_B(buf, kk, np) do { _Pragma("unroll") \
    for (int j = 0; j < 2; ++j) \
        bfp[j] = *(const short8*)&Bs[buf][(wn * 64 + ((np) * 2 + j) * 16 + lm) * 64 + \
                                          ((((kk) << 2) | quad) ^ ex) * 8]; } while (0)
#define MFMA16(np) do { _Pragma("unroll") \
    for (int mt = 0; mt < 8; ++mt) { \
        acc[mt][(np) * 2 + 0] = mfma_bf16(af[mt], bfp[0], acc[mt][(np) * 2 + 0]); \
        acc[mt][(np) * 2 + 1] = mfma_bf16(af[mt], bfp[1], acc[mt][(np) * 2 + 1]); \
    } } while (0)

    // prologue: tile0 (A+B) + tile1 (A); wait tile0, leave A(1) in flight
    stageA(0); stageB(0); stageA(1);
    asm volatile("s_waitcnt vmcnt(4)" ::: "memory");
    BARX();

    for (int t = 0; t < T; ++t) {
        const int buf = t & 1;
        short8 af[8], bfp[2];
        // ---- P0: A kk0 (8 reads) + B01 kk0 (2) ; stage B(t+1)
        READ_A(buf, 0); READ_B(buf, 0, 0);
        if (t + 1 < T) stageB(buf ^ 1);
        BARX(); LGKM0();
        __builtin_amdgcn_s_setprio(1); MFMA16(0); __builtin_amdgcn_s_setprio(0);
        BARX();
        // ---- P1: B23 kk0 (2 reads)
        READ_B(buf, 0, 1);
        BARX(); LGKM0();
        __builtin_amdgcn_s_setprio(1); MFMA16(1); __builtin_amdgcn_s_setprio(0);
        BARX();
        // ---- P2: A kk1 (8) + B01 kk1 (2)
        READ_A(buf, 1); READ_B(buf, 1, 0);
        BARX(); LGKM0();
        __builtin_amdgcn_s_setprio(1); MFMA16(0); __builtin_amdgcn_s_setprio(0);
        BARX();
        // ---- P3: B23 kk1 (2) ; stage A(t+2) ; counted vmcnt
        READ_B(buf, 1, 1);
        if (t + 2 < T) stageA(buf);
        BARX(); LGKM0();
        __builtin_amdgcn_s_setprio(1); MFMA16(1); __builtin_amdgcn_s_setprio(0);
        if (t + 2 < T) { asm volatile("s_waitcnt vmcnt(4)" ::: "memory"); }
        else           { asm volatile("s_waitcnt vmcnt(0)" ::: "memory"); }
        BARX();
    }
#undef READ_A
#undef READ_B
#undef MFMA16

#pragma unroll
    for (int mt = 0; mt < 8; ++mt) {
#pragma unroll
        for (int r = 0; r < 4; ++r) {
            const int row = m0 + wm * 128 + mt * 16 + quad * 4 + r;
#pragma unroll
            for (int nt = 0; nt < 4; ++nt) {
                const int col = n0 + wn * 64 + nt * 16 + lm;
                const size_t idx = (size_t)row * N + col;
                const float v = acc[mt][nt][r];
                if constexpr (EPI == 0) {
                    ((short*)Cout)[idx] = f2bf(v);
                } else if constexpr (EPI == 1) {
                    ((float*)Cout)[idx] = res[idx] + v;
                } else if constexpr (EPI == 2) {
                    ((short*)Cout)[idx] = f2bf(v / (1.0f + __expf(-v)));
                } else {
                    ((short*)Cout)[(size_t)blockIdx.z * M * N + idx] = f2bf(v);
                }
            }
        }
    }
}

// ---------------------------------------------------------------------------
// Split-K combine (4 bf16 partials): out = res + sum_{s<4} p[s]
// ---------------------------------------------------------------------------
__global__ __launch_bounds__(256) void combine_k4(
    const short* __restrict__ p, const float* __restrict__ res,
    float* __restrict__ out, int n)
{
    const int i = blockIdx.x * 256 + threadIdx.x;
    if (i * 4 < n) {
        float4 v = ((const float4*)res)[i];
#pragma unroll
        for (int s = 0; s < 4; ++s) {
            short4 ps = ((const short4*)(p + (size_t)s * n))[i];
            v.x += bf2f(ps.x); v.y += bf2f(ps.y);
            v.z += bf2f(ps.z); v.w += bf2f(ps.w);
        }
        ((float4*)out)[i] = v;
    }
}

// ---------------------------------------------------------------------------
// Fused split-K combine (4 bf16 partials) + RMSNorm: one block per token.
// ---------------------------------------------------------------------------
__global__ __launch_bounds__(256) void combine_rms4(
    const short* __restrict__ p, const float* __restrict__ res,
    const float* __restrict__ g, float* __restrict__ x2out,
    short* __restrict__ nout)
{
    const int t = blockIdx.x, tid = threadIdx.x;
    const int wave = tid >> 6, lane = tid & 63;
    const size_t i4 = (size_t)t * 256 + tid;  // float4 index
    float4 v = ((const float4*)res)[i4];
#pragma unroll
    for (int s = 0; s < 4; ++s) {
        short4 ps = ((const short4*)(p + (size_t)s * TOKENS * DIM))[i4];
        v.x += bf2f(ps.x); v.y += bf2f(ps.y);
        v.z += bf2f(ps.z); v.w += bf2f(ps.w);
    }
    ((float4*)x2out)[i4] = v;
    float ss = v.x * v.x + v.y * v.y + v.z * v.z + v.w * v.w;
#pragma unroll
    for (int d = 1; d < 64; d <<= 1) ss += __shfl_xor(ss, d, 64);
    __shared__ float red[4];
    if (lane == 0) red[wave] = ss;
    __syncthreads();
    float tot = red[0] + red[1] + red[2] + red[3];
    float rn = rsqrtf(tot * (1.0f / (float)DIM) + 1e-6f);
    const float4 gv = ((const float4*)g)[tid];
    short4 ov = make_short4(f2bf(v.x * rn * gv.x), f2bf(v.y * rn * gv.y),
                            f2bf(v.z * rn * gv.z), f2bf(v.w * rn * gv.w));
    ((short4*)nout)[i4] = ov;
}

// ---------------------------------------------------------------------------
// Flash attention, causal, fixed-max softmax. (R10/R11, unchanged.)
// K/V swizzled (free addressing, 0-conflict b128); P padded LP=72 (cheap
// scalar writes); lsum via ones-MFMA; band-hoisted softmax.
// ---------------------------------------------------------------------------
#define PLP 72
__global__ __launch_bounds__(256, 2) void attn_k(
    const short* __restrict__ qkv, const short* __restrict__ Vt,
    short* __restrict__ out)
{
    __shared__ short Ks[2][64 * 64];    // 16 KB (swizzled)
    __shared__ short Vts[2][64 * 64];   // 16 KB (swizzled)
    __shared__ short Ps[4][32 * PLP];   // 18 KB (padded, plain addressing)

    const int tid = threadIdx.x, wave = tid >> 6, lane = tid & 63;
    const int pair = wave >> 1, wv = wave & 1;
    const int lm = lane & 15, quad = lane >> 4;
    const int e = lm & 7;
    const int bh = blockIdx.x;
    const int qt = (gridDim.y - 1) - blockIdx.y;  // heavy blocks first
    const int b = bh >> 4, h = bh & 15;
    const int q0 = qt * 64;

    const int n  = qt + 1;           // total s-tiles
    const int nA = (n + 1) >> 1;     // tiles for pair A
    const int nP = pair ? (n >> 1) : nA;
    const int sbase = pair ? nA : 0;

    const int tp = tid & 127;        // thread index within pair
    const int rr = tp >> 3, cg = tp & 7;
    const int pcol = (cg ^ (rr & 7)) * 8;   // XOR-swizzled chunk (K/V staging)

    // Q fragments (loop-invariant, direct to registers)
    const short* qb = qkv + ((size_t)(b * TSEQ + q0)) * 3072 + h * 64;
    short8 aq[2][2];
#pragma unroll
    for (int mt = 0; mt < 2; ++mt)
#pragma unroll
        for (int kk = 0; kk < 2; ++kk)
            aq[mt][kk] = *(const short8*)(qb + (size_t)(wv * 32 + mt * 16 + lm) * 3072 + kk * 32 + quad * 8);

    const short* kb  = qkv + (size_t)b * TSEQ * 3072 + 1024 + h * 64;
    const short* vtb = Vt + (size_t)bh * 64 * TSEQ;

    const short ONEBF = (short)0x3F80;  // bf16 1.0
    const short8 ones8 = {ONEBF, ONEBF, ONEBF, ONEBF, ONEBF, ONEBF, ONEBF, ONEBF};

    const f32x4 zero = {0.f, 0.f, 0.f, 0.f};
    f32x4 o_acc[2][4];
    f32x4 lacc[2];  // l[q] per mt
#pragma unroll
    for (int mt = 0; mt < 2; ++mt) {
#pragma unroll
        for (int t = 0; t < 4; ++t) o_acc[mt][t] = zero;
        lacc[mt] = zero;
    }

    // initial register prefetch of this pair's first tile
    short8 kr[4], vr[4];
    if (nP > 0) {
        const size_t s0i = (size_t)sbase * 64;
#pragma unroll
        for (int j = 0; j < 4; ++j) {
            kr[j] = *(const short8*)(kb + (s0i + rr + j * 16) * 3072 + cg * 8);
            vr[j] = *(const short8*)(vtb + (size_t)(rr + j * 16) * TSEQ + s0i + cg * 8);
        }
    }

    for (int it = 0; it < nA; ++it) {
        const int st = sbase + it;
        const bool act = it < nP;
        __syncthreads();
        if (act) {
#pragma unroll
            for (int j = 0; j < 4; ++j) {
                *(short8*)&Ks[pair][(rr + j * 16) * 64 + pcol] = kr[j];
                *(short8*)&Vts[pair][(rr + j * 16) * 64 + pcol] = vr[j];
            }
        }
        __syncthreads();
        if (act && it + 1 < nP) {
            const size_t sn = (size_t)(st + 1) * 64;
#pragma unroll
            for (int j = 0; j < 4; ++j) {
                kr[j] = *(const short8*)(kb + (sn + rr + j * 16) * 3072 + cg * 8);
                vr[j] = *(const short8*)(vtb + (size_t)(rr + j * 16) * TSEQ + sn + cg * 8);
            }
        }
        if (!act) continue;

        // QK^T  (swizzled reads: chunk = (kk*4+quad) ^ (lm&7))
        f32x4 sa[2][4];
#pragma unroll
        for (int mt = 0; mt < 2; ++mt)
#pragma unroll
            for (int nt = 0; nt < 4; ++nt) sa[mt][nt] = zero;
#pragma unroll
        for (int kk = 0; kk < 2; ++kk) {
#pragma unroll
            for (int nt = 0; nt < 4; ++nt) {
                short8 bk = *(const short8*)&Ks[pair][(nt * 16 + lm) * 64 +
                                                     ((((kk << 2) | quad) ^ e) << 3)];
                sa[0][nt] = mfma_bf16(aq[0][kk], bk, sa[0][nt]);
                sa[1][nt] = mfma_bf16(aq[1][kk], bk, sa[1][nt]);
            }
        }

        // softmax (fixed-max) -> per-wave P buffer; band hoisted out
        const int s0 = st * 64;
        if (st != qt) {
#pragma unroll
            for (int mt = 0; mt < 2; ++mt)
#pragma unroll
                for (int nt = 0; nt < 4; ++nt)
#pragma unroll
                    for (int r = 0; r < 4; ++r) {
                        float p = exp2f(0.18033688011112042f * sa[mt][nt][r]);
                        Ps[wave][(mt * 16 + quad * 4 + r) * PLP + nt * 16 + lm] =
                            (short)(__builtin_bit_cast(uint32_t, p) >> 16);
                    }
        } else {
#pragma unroll
            for (int mt = 0; mt < 2; ++mt) {
                const int qrow = q0 + wv * 32 + mt * 16 + quad * 4;
#pragma unroll
                for (int nt = 0; nt < 4; ++nt) {
                    const int col = s0 + nt * 16 + lm;
#pragma unroll
                    for (int r = 0; r < 4; ++r) {
                        float p = exp2f(0.18033688011112042f * sa[mt][nt][r]);
                        if (col > qrow + r) p = 0.f;
                        Ps[wave][(mt * 16 + quad * 4 + r) * PLP + nt * 16 + lm] =
                            (short)(__builtin_bit_cast(uint32_t, p) >> 16);
                    }
                }
            }
        }

        // P @ V  (+ ones-MFMA accumulates l[q] into lacc)
#pragma unroll
        for (int kk = 0; kk < 2; ++kk) {
            short8 ap0 = *(const short8*)&Ps[wave][lm * PLP + kk * 32 + quad * 8];
            short8 ap1 = *(const short8*)&Ps[wave][(16 + lm) * PLP + kk * 32 + quad * 8];
            lacc[0] = mfma_bf16(ap0, ones8, lacc[0]);
            lacc[1] = mfma_bf16(ap1, ones8, lacc[1]);
#pragma unroll
            for (int t = 0; t < 4; ++t) {
                short8 bv = *(const short8*)&Vts[pair][(t * 16 + lm) * 64 +
                                                       ((((kk << 2) | quad) ^ e) << 3)];
                o_acc[0][t] = mfma_bf16(ap0, bv, o_acc[0][t]);
                o_acc[1][t] = mfma_bf16(ap1, bv, o_acc[1][t]);
            }
        }
    }

    // cross-pair combine through LDS (Ks/Vts/Ps dead after final barrier)
    __syncthreads();
    float* Ob = (float*)&Ks[0][0];    // 64 rows x 64 cols fp32 = 16384B (= Ks)
    float* Lb = (float*)&Ps[0][0];    // 64 floats
    if (pair == 1) {
#pragma unroll
        for (int mt = 0; mt < 2; ++mt)
#pragma unroll
            for (int t = 0; t < 4; ++t)
#pragma unroll
                for (int r = 0; r < 4; ++r)
                    Ob[(wv * 32 + mt * 16 + quad * 4 + r) * 64 + t * 16 + lm] = o_acc[mt][t][r];
        if (lm == 0) {
#pragma unroll
            for (int mt = 0; mt < 2; ++mt)
#pragma unroll
                for (int r = 0; r < 4; ++r)
                    Lb[wv * 32 + mt * 16 + quad * 4 + r] = lacc[mt][r];
        }
    }
    __syncthreads();
    if (pair == 0) {
#pragma unroll
        for (int mt = 0; mt < 2; ++mt) {
#pragma unroll
            for (int r = 0; r < 4; ++r) {
                const int lrow = wv * 32 + mt * 16 + quad * 4 + r;
                float ltot = lacc[mt][r] + Lb[lrow];
                const float inv = 1.0f / ltot;
                const int token = b * TSEQ + q0 + lrow;
#pragma unroll
                for (int t = 0; t < 4; ++t) {
                    float o = o_acc[mt][t][r] + Ob[lrow * 64 + t * 16 + lm];
                    out[(size_t)token * 1024 + h * 64 + t * 16 + lm] = f2bf(o * inv);
                }
            }
        }
    }
}

// ---------------------------------------------------------------------------
// Orchestration
// ---------------------------------------------------------------------------
extern "C" void kernel_launch(void* const* d_in, const int* in_sizes, int n_in,
                              void* d_out, int out_size, void* d_ws, size_t ws_size,
                              hipStream_t stream)
{
    const float* x      = (const float*)d_in[0];
    // d_in[1] = mask (causal, implemented analytically)
    const float* wq     = (const float*)d_in[2];
    const float* wk     = (const float*)d_in[3];
    const float* wv     = (const float*)d_in[4];
    const float* wo     = (const float*)d_in[5];
    const float* w1     = (const float*)d_in[6];
    const float* w2     = (const float*)d_in[7];
    const float* g_attn = (const float*)d_in[8];
    const float* g_ffn  = (const float*)d_in[9];
    float* out = (float*)d_out;

    char* ws = (char*)d_ws;
    const size_t MB = 1024 * 1024;
    short* Wqkv_t = (short*)(ws + 0);
    short* Wo_t   = (short*)(ws + 6 * MB);
    short* W1_t   = (short*)(ws + 8 * MB);
    short* xn     = (short*)(ws + 16 * MB);
    short* hbuf   = (short*)(ws + 24 * MB);
    short* qkv    = (short*)(ws + 32 * MB);
    short* pbufO  = (short*)(ws + 32 * MB);
    short* Vt     = (short*)(ws + 64 * MB);
    float* x2     = (float*)(ws + 64 * MB);
    short* W2_t   = (short*)(ws + 80 * MB);
    short* pbuf2  = (short*)(ws + 0);

    dim3 blk(256);

    transpose_w<<<dim3(16, 16), blk, 0, stream>>>(wq, Wqkv_t, 1024, 1024);
    transpose_w<<<dim3(16, 16), blk, 0, stream>>>(wk, Wqkv_t + (size_t)1024 * 1024, 1024, 1024);
    transpose_w<<<dim3(16, 16), blk, 0, stream>>>(wv, Wqkv_t + (size_t)2048 * 1024, 1024, 1024);
    transpose_w<<<dim3(16, 16), blk, 0, stream>>>(wo, Wo_t, 1024, 1024);
    transpose_w<<<dim3(64, 16), blk, 0, stream>>>(w1, W1_t, 1024, 4096);
    transpose_w<<<dim3(16, 64), blk, 0, stream>>>(w2, W2_t, 4096, 1024);

    rmsnorm_k<<<TOKENS, blk, 0, stream>>>(x, g_attn, xn);

    // qkv = xn @ [Wq|Wk|Wv]   (grid m-fastest, 2-phase: 768 blocks)
    gemm_bt<0><<<dim3(TOKENS / 128, 3072 / 128), blk, 0, stream>>>(
        xn, Wqkv_t, qkv, nullptr, TOKENS, 3072, 1024);

    transpose_v<<<dim3(TSEQ / 64, 32), blk, 0, stream>>>(qkv, Vt);

    attn_k<<<dim3(32, TSEQ / 64), dim3(256), 0, stream>>>(qkv, Vt, xn);

    // O-proj split-K=4 (2-phase: T=4), bf16 partials into dead qkv
    gemm_bt<3><<<dim3(TOKENS / 128, 1024 / 128, 4), blk, 0, stream>>>(
        xn, Wo_t, pbufO, nullptr, TOKENS, 1024, 1024);

    // x2 = x + sum p ; hbuf = rmsnorm(x2)*g_ffn   (fused)
    combine_rms4<<<TOKENS, blk, 0, stream>>>(pbufO, x, g_ffn, x2, hbuf);

    // t = silu(h @ W1): 8-phase 256^2 (256 blocks, T=16 — same regime that
    // took FFN2 from 67.9 to <52us in R11)
    gemm8_bt<2><<<dim3(TOKENS / 256, HIDDEN / 256), dim3(512), 0, stream>>>(
        hbuf, W1_t, qkv, nullptr, TOKENS, HIDDEN, 1024);

    // FFN2 split-K=4: 8-phase 256^2 (deep-K regime), bf16 partials
    gemm8_bt<3><<<dim3(TOKENS / 256, 1024 / 256, 4), dim3(512), 0, stream>>>(
        qkv, W2_t, pbuf2, nullptr, TOKENS, 1024, HIDDEN);

    combine_k4<<<dim3(TOKENS * DIM / 4 / 256), blk, 0, stream>>>(
        pbuf2, x2, out, TOKENS * DIM);
}